// Round 9
// baseline (316.088 us; speedup 1.0000x reference)
//
#include <hip/hip_runtime.h>

#define BB 4
#define SS 2048
#define DD 1024
#define HH 16
#define DH 64

typedef __attribute__((ext_vector_type(8))) short short8;
typedef __attribute__((ext_vector_type(4))) float floatx4;

static __device__ __forceinline__ float b2f(unsigned short u) {
  union { unsigned int i; float f; } c; c.i = ((unsigned int)u) << 16; return c.f;
}
static __device__ __forceinline__ unsigned short f2b(float f) {
  union { float ff; unsigned int i; } c; c.ff = f;
  unsigned int x = c.i;
  return (unsigned short)((x + 0x7fffu + ((x >> 16) & 1u)) >> 16);
}

#define MFMA16(a, b, c) __builtin_amdgcn_mfma_f32_16x16x32_bf16((a), (b), (c), 0, 0, 0)

// async global->LDS, 16 B per lane; LDS dest = wave-uniform base + lane*16
#define ASYNC16(g, l)                                                        \
  __builtin_amdgcn_global_load_lds(                                          \
      (const __attribute__((address_space(1))) unsigned int*)(g),            \
      (__attribute__((address_space(3))) unsigned int*)(l), 16, 0, 0)

// ---------------------------------------------------------------------------
// cvt_all: one-shot fp32 -> bf16 for x and the 4 weight matrices.
// ---------------------------------------------------------------------------
__global__ __launch_bounds__(256) void cvt_all(
    const float* __restrict__ x, const float* __restrict__ wq,
    const float* __restrict__ wk, const float* __restrict__ wv,
    const float* __restrict__ wo,
    unsigned short* __restrict__ x16, unsigned short* __restrict__ w16,
    unsigned short* __restrict__ wo16) {
  const int blk = blockIdx.x;
  const float* src;
  unsigned short* dst;
  size_t off;
  if (blk < 4096)      { src = x;  dst = x16;             off = (size_t)blk * 2048; }
  else if (blk < 4608) { src = wq; dst = w16;             off = (size_t)(blk - 4096) * 2048; }
  else if (blk < 5120) { src = wk; dst = w16 + (1 << 20); off = (size_t)(blk - 4608) * 2048; }
  else if (blk < 5632) { src = wv; dst = w16 + (2 << 20); off = (size_t)(blk - 5120) * 2048; }
  else                 { src = wo; dst = wo16;            off = (size_t)(blk - 5632) * 2048; }
  const int t = threadIdx.x;
  const float4* s4 = (const float4*)(src + off) + t * 2;
  const float4 a = s4[0], bq = s4[1];
  union { short8 v; unsigned short u[8]; } p;
  p.u[0] = f2b(a.x);  p.u[1] = f2b(a.y);  p.u[2] = f2b(a.z);  p.u[3] = f2b(a.w);
  p.u[4] = f2b(bq.x); p.u[5] = f2b(bq.y); p.u[6] = f2b(bq.z); p.u[7] = f2b(bq.w);
  *(short8*)(dst + off + (size_t)t * 8) = p.v;
}

// ---------------------------------------------------------------------------
// qkv_gemm (m97-style): C[8192,3072] = x16 @ w16^T, all bf16. 128x128 tile,
// BK=32, unpadded LDS, global_load_lds width=16.
// Epilogue: q,k -> [B,H,S,DH]; v -> vt[B,H,DH,S].
// ---------------------------------------------------------------------------
__global__ __launch_bounds__(256) void qkv_gemm(
    const unsigned short* __restrict__ x16, const unsigned short* __restrict__ w16,
    unsigned short* __restrict__ qb, unsigned short* __restrict__ kb,
    unsigned short* __restrict__ vt) {
  __shared__ __align__(16) unsigned short As[128 * 32];
  __shared__ __align__(16) unsigned short Bs[128 * 32];

  const int blk = blockIdx.x;           // 64 m-tiles (fast) x 24 n-tiles
  const int m0 = (blk & 63) * 128;
  const int nblk = blk >> 6;
  const int mat = nblk >> 3;
  const int c0 = (nblk & 7) * 128;

  const int tid = threadIdx.x;
  const int lane = tid & 63, wave = tid >> 6;
  const int wm = (wave >> 1) * 64, wn = (wave & 1) * 64;
  const int quad = lane >> 4, l15 = lane & 15;

  const int srow = lane >> 2;
  const int sc = (lane & 3) * 8;
  const unsigned short* ag = x16 + (size_t)(m0 + wave * 32 + srow) * DD + sc;
  const unsigned short* bg = w16 + (size_t)(nblk * 128 + wave * 32 + srow) * DD + sc;
  unsigned short* al = &As[wave * 1024];
  unsigned short* bl = &Bs[wave * 1024];

  floatx4 acc[4][4] = {};

  for (int k0 = 0; k0 < DD; k0 += 32) {
    ASYNC16(ag + k0, al);
    ASYNC16(ag + 16 * DD + k0, al + 512);
    ASYNC16(bg + k0, bl);
    ASYNC16(bg + 16 * DD + k0, bl + 512);
    __syncthreads();
    short8 af[4], bf[4];
#pragma unroll
    for (int mt = 0; mt < 4; ++mt)
      af[mt] = *(const short8*)&As[(wm + mt * 16 + l15) * 32 + quad * 8];
#pragma unroll
    for (int nt = 0; nt < 4; ++nt)
      bf[nt] = *(const short8*)&Bs[(wn + nt * 16 + l15) * 32 + quad * 8];
#pragma unroll
    for (int mt = 0; mt < 4; ++mt)
#pragma unroll
      for (int nt = 0; nt < 4; ++nt)
        acc[mt][nt] = MFMA16(af[mt], bf[nt], acc[mt][nt]);
    __syncthreads();
  }

  if (mat < 2) {
    unsigned short* dst = (mat == 0) ? qb : kb;
#pragma unroll
    for (int mt = 0; mt < 4; ++mt) {
#pragma unroll
      for (int nt = 0; nt < 4; ++nt) {
#pragma unroll
        for (int r = 0; r < 4; ++r) {
          const int row = m0 + wm + mt * 16 + quad * 4 + r;
          const int c = c0 + wn + nt * 16 + l15;
          const int h = c >> 6, d = c & 63;
          const int b = row >> 11, s = row & (SS - 1);
          dst[(((size_t)(b * HH + h)) * SS + s) * DH + d] = f2b(acc[mt][nt][r]);
        }
      }
    }
  } else {
#pragma unroll
    for (int mt = 0; mt < 4; ++mt) {
#pragma unroll
      for (int nt = 0; nt < 4; ++nt) {
        const int c = c0 + wn + nt * 16 + l15;
        const int h = c >> 6, d = c & 63;
        const int row0 = m0 + wm + mt * 16 + quad * 4;
        const int b = row0 >> 11, s0 = row0 & (SS - 1);
        union { unsigned short u[4]; uint2 v2; } pk;
#pragma unroll
        for (int r = 0; r < 4; ++r) pk.u[r] = f2b(acc[mt][nt][r]);
        *(uint2*)&vt[(((size_t)(b * HH + h)) * DH + d) * SS + s0] = pk.v2;
      }
    }
  }
}

// ---------------------------------------------------------------------------
// rope: in-place RoPE on q and k, both [B,H,S,DH] bf16. grid = B*S.
// ---------------------------------------------------------------------------
__global__ __launch_bounds__(256) void rope_kernel(
    unsigned short* __restrict__ q, unsigned short* __restrict__ k,
    const int* __restrict__ tpos) {
  const int row = blockIdx.x;
  const int b = row >> 11, s = row & (SS - 1);
  const float pf = (float)tpos[row];
  const int t = threadIdx.x;
#pragma unroll
  for (int i = 0; i < 2; ++i) {
    const int pr = t + i * 256;
    const int h = pr >> 5, j = pr & 31;
    const float inv = exp2f((float)j * -0.41524101186091903f);
    float sv, cv;
    sincosf(pf * inv, &sv, &cv);
    const size_t idx = (((size_t)(b * HH + h)) * SS + s) * DH + 2 * j;
    const float qe = b2f(q[idx]), qo = b2f(q[idx + 1]);
    q[idx]     = f2b(qe * cv - qo * sv);
    q[idx + 1] = f2b(qe * sv + qo * cv);
    const float ke = b2f(k[idx]), ko = b2f(k[idx + 1]);
    k[idx]     = f2b(ke * cv - ko * sv);
    k[idx + 1] = f2b(ke * sv + ko * cv);
  }
}

// ---------------------------------------------------------------------------
// attn_flash v4: 128-row Q tile per block (wave w owns rows w*32..w*32+31 as
// two 16-row groups). Each 64-key K/V stage feeds 32 MFMA (2x the old ratio).
// blk = pr*64 + bh (bh fastest -> head's blocks share an XCD; L2-resident K/V).
// Pair {pr, 15-pr} -> exactly 34 K-iterations per block. Fixed-shift softmax
// exp2(fma(s,c1,c2)) = exp(s/8 - 8), exact. Register prefetch of next K/V.
// LDS 55.3 KB -> 2 blocks/CU; 512 blocks = 2 full rounds per XCD.
// ---------------------------------------------------------------------------
#define LDK 72

__global__ __launch_bounds__(256) void attn_flash(
    const unsigned short* __restrict__ q, const unsigned short* __restrict__ k,
    const unsigned short* __restrict__ vt, unsigned short* __restrict__ ao) {
  const int blk = blockIdx.x;          // pr*64 + bh
  const int bh = blk & 63, pr = blk >> 6;    // pr in 0..7
  const int b = bh >> 4, h = bh & 15;
  const size_t kvbase = (size_t)bh * SS * DH;
  const size_t vtbase = (size_t)bh * DH * SS;

  const int tid = threadIdx.x;
  const int lane = tid & 63, wave = tid >> 6;
  const int quad = lane >> 4, l15 = lane & 15;

  __shared__ __align__(16) unsigned short Qs[128 * LDK];  // 18.4 KB
  __shared__ __align__(16) unsigned short Ks[64 * LDK];   //  9.2 KB [key][d]
  __shared__ __align__(16) unsigned short Vs[64 * LDK];   //  9.2 KB [d][key]
  __shared__ __align__(16) unsigned short Ps[128 * LDK];  // 18.4 KB

  const int sr = tid >> 2, sc = (tid & 3) * 16;   // K/V staging row/col
  const unsigned short* kg0 = k + kvbase + (size_t)sr * DH + sc;
  const unsigned short* vg0 = vt + vtbase + (size_t)sr * SS + sc;

  // exp(s*0.125 - 8) == exp2(s*0.125*log2e - 8*log2e)
  const float C1 = 0.18033688f, C2 = -11.54156037f;

  for (int phase = 0; phase < 2; ++phase) {
    const int qt = phase ? (15 - pr) : pr;      // 128-row q-tile index
    const int q0 = qt * 128;
    const int ktmax = 2 * qt + 1;

    // stage Q: 128 rows x 64 cols; thread -> (row tid>>1, col (tid&1)*32)
    {
      const int r = tid >> 1, c = (tid & 1) * 32;
      const uint4* g = (const uint4*)(q + kvbase + (size_t)(q0 + r) * DH + c);
      uint4 d0 = g[0], d1 = g[1], d2 = g[2], d3 = g[3];
      *(uint4*)&Qs[r * LDK + c] = d0;
      *(uint4*)&Qs[r * LDK + c + 8] = d1;
      *(uint4*)&Qs[r * LDK + c + 16] = d2;
      *(uint4*)&Qs[r * LDK + c + 24] = d3;
    }
    __syncthreads();
    short8 aq[2][2];
#pragma unroll
    for (int g = 0; g < 2; ++g) {
      const int qr = wave * 32 + g * 16 + l15;
      aq[g][0] = *(const short8*)&Qs[qr * LDK + quad * 8];
      aq[g][1] = *(const short8*)&Qs[qr * LDK + 32 + quad * 8];
    }

    floatx4 oacc[2][4] = {};
    float lrow[2][4] = {};

    // prefetch tile 0
    uint4 kra = *(const uint4*)(kg0);
    uint4 krb = *(const uint4*)(kg0 + 8);
    uint4 vra = *(const uint4*)(vg0);
    uint4 vrb = *(const uint4*)(vg0 + 8);

    for (int kt = 0; kt <= ktmax; ++kt) {
      __syncthreads();   // all waves done reading previous Ks/Vs
      *(uint4*)&Ks[sr * LDK + sc] = kra;
      *(uint4*)&Ks[sr * LDK + sc + 8] = krb;
      *(uint4*)&Vs[sr * LDK + sc] = vra;
      *(uint4*)&Vs[sr * LDK + sc + 8] = vrb;
      __syncthreads();

      if (kt < ktmax) {  // prefetch next tile; latency hidden under compute
        const unsigned short* kg = kg0 + (size_t)(kt + 1) * (64 * DH);
        const unsigned short* vg = vg0 + (size_t)(kt + 1) * 64;
        kra = *(const uint4*)(kg);
        krb = *(const uint4*)(kg + 8);
        vra = *(const uint4*)(vg);
        vrb = *(const uint4*)(vg + 8);
      }

      // K/V fragments shared by both q-row groups
      short8 bk[4][2], bv[4][2];
#pragma unroll
      for (int n = 0; n < 4; ++n) {
        bk[n][0] = *(const short8*)&Ks[(n * 16 + l15) * LDK + quad * 8];
        bk[n][1] = *(const short8*)&Ks[(n * 16 + l15) * LDK + 32 + quad * 8];
        bv[n][0] = *(const short8*)&Vs[(n * 16 + l15) * LDK + quad * 8];
        bv[n][1] = *(const short8*)&Vs[(n * 16 + l15) * LDK + 32 + quad * 8];
      }

      const int e = (kt - 2 * qt) * 64;   // key offset - row offset (局部)
#pragma unroll
      for (int g = 0; g < 2; ++g) {
        const int base = wave * 32 + g * 16;
        if (base + 16 <= e) continue;           // group fully masked (uniform)
        const bool needmask = (base < e + 63);

        // QK^T: 4 key-subtiles x 2 MFMA over d
        floatx4 st[4];
#pragma unroll
        for (int n = 0; n < 4; ++n) {
          floatx4 z = {0.f, 0.f, 0.f, 0.f};
          z = MFMA16(aq[g][0], bk[n][0], z);
          z = MFMA16(aq[g][1], bk[n][1], z);
          st[n] = z;
        }

        float pb[4][4];
#pragma unroll
        for (int r = 0; r < 4; ++r) {
          const int qeff = base + quad * 4 + r - e;
#pragma unroll
          for (int n = 0; n < 4; ++n) {
            const bool msk = needmask && (n * 16 + l15 > qeff);
            const float p = msk ? 0.f : exp2f(fmaf(st[n][r], C1, C2));
            pb[n][r] = p;
            lrow[g][r] += p;
          }
        }

        // P: C-layout regs -> LDS -> A-layout frags (wave-local rows)
#pragma unroll
        for (int r = 0; r < 4; ++r)
#pragma unroll
          for (int n = 0; n < 4; ++n)
            Ps[(base + quad * 4 + r) * LDK + n * 16 + l15] = f2b(pb[n][r]);
        short8 pf0 = *(const short8*)&Ps[(base + l15) * LDK + quad * 8];
        short8 pf1 = *(const short8*)&Ps[(base + l15) * LDK + 32 + quad * 8];

        // PV: 4 d-subtiles x 2 MFMA over keys
#pragma unroll
        for (int n = 0; n < 4; ++n) {
          oacc[g][n] = MFMA16(pf0, bv[n][0], oacc[g][n]);
          oacc[g][n] = MFMA16(pf1, bv[n][1], oacc[g][n]);
        }
      }
    }

    // epilogue per group: reduce l across the 16 col-lanes, write out
#pragma unroll
    for (int g = 0; g < 2; ++g) {
      float linv[4];
#pragma unroll
      for (int r = 0; r < 4; ++r) {
        float t = lrow[g][r];
#pragma unroll
        for (int off = 1; off < 16; off <<= 1) t += __shfl_xor(t, off, 64);
        linv[r] = 1.0f / t;
      }
#pragma unroll
      for (int n = 0; n < 4; ++n) {
#pragma unroll
        for (int r = 0; r < 4; ++r) {
          const int qa = q0 + wave * 32 + g * 16 + quad * 4 + r;
          const int d = n * 16 + l15;
          ao[((size_t)(b * SS + qa)) * DD + h * DH + d] = f2b(oacc[g][n][r] * linv[r]);
        }
      }
    }
  }
}

// ---------------------------------------------------------------------------
// o_gemm: out[8192,1024](fp32) = ab[8192,1024](bf16) @ wo16[1024,1024]^T(bf16)
// ---------------------------------------------------------------------------
__global__ __launch_bounds__(256) void o_gemm(
    const unsigned short* __restrict__ a, const unsigned short* __restrict__ w16,
    float* __restrict__ out) {
  __shared__ __align__(16) unsigned short As[128 * 32];
  __shared__ __align__(16) unsigned short Bs[128 * 32];

  const int blk = blockIdx.x;          // 64 m x 8 n
  const int m0 = (blk >> 3) * 128;
  const int n0 = (blk & 7) * 128;

  const int tid = threadIdx.x;
  const int lane = tid & 63, wave = tid >> 6;
  const int wm = (wave >> 1) * 64, wn = (wave & 1) * 64;
  const int quad = lane >> 4, l15 = lane & 15;

  const int srow = lane >> 2;
  const int sc = (lane & 3) * 8;
  const unsigned short* ag = a + (size_t)(m0 + wave * 32 + srow) * DD + sc;
  const unsigned short* bg = w16 + (size_t)(n0 + wave * 32 + srow) * DD + sc;
  unsigned short* al = &As[wave * 1024];
  unsigned short* bl = &Bs[wave * 1024];

  floatx4 acc[4][4] = {};

  for (int k0 = 0; k0 < DD; k0 += 32) {
    ASYNC16(ag + k0, al);
    ASYNC16(ag + 16 * DD + k0, al + 512);
    ASYNC16(bg + k0, bl);
    ASYNC16(bg + 16 * DD + k0, bl + 512);
    __syncthreads();
    short8 af[4], bf[4];
#pragma unroll
    for (int mt = 0; mt < 4; ++mt)
      af[mt] = *(const short8*)&As[(wm + mt * 16 + l15) * 32 + quad * 8];
#pragma unroll
    for (int nt = 0; nt < 4; ++nt)
      bf[nt] = *(const short8*)&Bs[(wn + nt * 16 + l15) * 32 + quad * 8];
#pragma unroll
    for (int mt = 0; mt < 4; ++mt)
#pragma unroll
      for (int nt = 0; nt < 4; ++nt)
        acc[mt][nt] = MFMA16(af[mt], bf[nt], acc[mt][nt]);
    __syncthreads();
  }

#pragma unroll
  for (int mt = 0; mt < 4; ++mt) {
#pragma unroll
    for (int nt = 0; nt < 4; ++nt) {
#pragma unroll
      for (int r = 0; r < 4; ++r) {
        const int row = m0 + wm + mt * 16 + quad * 4 + r;
        const int col = n0 + wn + nt * 16 + l15;
        out[(size_t)row * DD + col] = acc[mt][nt][r];
      }
    }
  }
}

extern "C" void kernel_launch(void* const* d_in, const int* in_sizes, int n_in,
                              void* d_out, int out_size, void* d_ws, size_t ws_size,
                              hipStream_t stream) {
  const float* x  = (const float*)d_in[0];
  const int* tpos = (const int*)d_in[1];
  const float* wq = (const float*)d_in[2];
  const float* wk = (const float*)d_in[3];
  const float* wv = (const float*)d_in[4];
  const float* wo = (const float*)d_in[5];

  const size_t N = (size_t)BB * SS * DD;           // 8,388,608
  unsigned short* qb  = (unsigned short*)d_out;    // bf16 q [B,H,S,DH]
  unsigned short* w16 = qb + N;                    // bf16 q|k|v weights (6.3 MB)
  unsigned short* kb   = (unsigned short*)d_ws;    // bf16 k [B,H,S,DH]
  unsigned short* vb   = kb + N;                   // bf16 v^T [B,H,DH,S]
  unsigned short* ab   = vb + N;                   // bf16 attn [B,S,D]
  unsigned short* wo16 = ab + N;                   // bf16 wo
  unsigned short* x16  = ab;                       // alias: dead before attn writes ab
  float* out = (float*)d_out;

  cvt_all<<<6144, 256, 0, stream>>>(x, wq, wk, wv, wo, x16, w16, wo16);
  qkv_gemm<<<64 * 24, 256, 0, stream>>>(x16, w16, qb, kb, vb);
  rope_kernel<<<BB * SS, 256, 0, stream>>>(qb, kb, tpos);
  attn_flash<<<8 * 64, 256, 0, stream>>>(qb, kb, vb, ab);
  o_gemm<<<64 * 8, 256, 0, stream>>>(ab, wo16, out);
}